// Round 15
// baseline (221.355 us; speedup 1.0000x reference)
//
#include <hip/hip_runtime.h>
#include <hip/hip_bf16.h>
#include <math.h>

#define B_   2
#define H_   16
#define NSEQ 1024
#define DM   1024
#define DKV  64
#define NSPLIT 16
#define LNEPS 1e-5f

typedef __attribute__((ext_vector_type(8))) short s16x8;
typedef __attribute__((ext_vector_type(4))) float f32x4;
typedef __attribute__((ext_vector_type(4))) unsigned u32x4;

__device__ inline short f2bf(float f) {
    __hip_bfloat16 h = __float2bfloat16(f);
    return *reinterpret_cast<short*>(&h);
}
__device__ inline float bf2f(short s) {
    unsigned u = ((unsigned)(unsigned short)s) << 16;
    return __uint_as_float(u);
}

// async global->LDS; LDS dest = wave-uniform base + lane*width; global src per-lane.
__device__ __forceinline__ void gll16(const void* g, void* l) {
    __builtin_amdgcn_global_load_lds(
        (const __attribute__((address_space(1))) unsigned int*)g,
        (__attribute__((address_space(3))) unsigned int*)l, 16, 0, 0);
}
__device__ __forceinline__ void gll4(const void* g, void* l) {
    __builtin_amdgcn_global_load_lds(
        (const __attribute__((address_space(1))) unsigned int*)g,
        (__attribute__((address_space(3))) unsigned int*)l, 4, 0, 0);
}

#define SYNC_STAGE do { asm volatile("s_waitcnt vmcnt(0)" ::: "memory"); __syncthreads(); } while (0)

// ---------------- mask dtype detection ----------------
__global__ void detect_mask(const unsigned* __restrict__ mask_words, int* __restrict__ flag) {
    unsigned f = 0;
    for (int i = 0; i < 256; ++i) f |= (mask_words[i] > 1u) ? 1u : 0u;
    *flag = (int)f;   // 1 => packed uint8 bools, 0 => int32 0/1
}

// ---------------- W[K][N] f32 -> Wt[N][K] bf16 (4 weights in one launch) ----------------
__global__ __launch_bounds__(256) void castT4_bf16(
    const float* __restrict__ w0, const float* __restrict__ w1,
    const float* __restrict__ w2, const float* __restrict__ w3,
    short* __restrict__ t0, short* __restrict__ t1,
    short* __restrict__ t2, short* __restrict__ t3) {
    const float* W = blockIdx.z == 0 ? w0 : (blockIdx.z == 1 ? w1 : (blockIdx.z == 2 ? w2 : w3));
    short* Wt      = blockIdx.z == 0 ? t0 : (blockIdx.z == 1 ? t1 : (blockIdx.z == 2 ? t2 : t3));
    __shared__ float tl[32][33];
    const int k0 = blockIdx.y * 32, n0 = blockIdx.x * 32;
    const int r = threadIdx.x >> 3, c4 = (threadIdx.x & 7) * 4;
    *(float4*)&tl[r][c4] = *(const float4*)(W + (size_t)(k0 + r) * DM + n0 + c4);
    __syncthreads();
    unsigned u0 = (unsigned short)f2bf(tl[c4+0][r]) | ((unsigned)(unsigned short)f2bf(tl[c4+1][r]) << 16);
    unsigned u1 = (unsigned short)f2bf(tl[c4+2][r]) | ((unsigned)(unsigned short)f2bf(tl[c4+3][r]) << 16);
    uint2 pk; pk.x = u0; pk.y = u1;
    *(uint2*)(Wt + (size_t)(n0 + r) * DM + k0 + c4) = pk;
}

// ---------------- shared GEMM core pieces ----------------
__device__ inline void loadAf32(const float* p, s16x8& a0, s16x8& a1) {
    f32x4 v0 = *(const f32x4*)p,       v1 = *(const f32x4*)(p + 4);
    f32x4 v2 = *(const f32x4*)(p + 8), v3 = *(const f32x4*)(p + 12);
    a0[0]=f2bf(v0[0]); a0[1]=f2bf(v0[1]); a0[2]=f2bf(v0[2]); a0[3]=f2bf(v0[3]);
    a0[4]=f2bf(v1[0]); a0[5]=f2bf(v1[1]); a0[6]=f2bf(v1[2]); a0[7]=f2bf(v1[3]);
    a1[0]=f2bf(v2[0]); a1[1]=f2bf(v2[1]); a1[2]=f2bf(v2[2]); a1[3]=f2bf(v2[3]);
    a1[4]=f2bf(v3[0]); a1[5]=f2bf(v3[1]); a1[6]=f2bf(v3[2]); a1[7]=f2bf(v3[3]);
}

// ---------------- fused QKV projection: 3 GEMMs in one launch ----------------
__global__ __launch_bounds__(256) void gemm_qkv(
    const float* __restrict__ qin, const float* __restrict__ kin, const float* __restrict__ vin,
    const short* __restrict__ Wcat,     // Wtq|Wtk|Wtv contiguous, each [DM][DM]
    const float* __restrict__ bq, const float* __restrict__ bk, const float* __restrict__ bv,
    short* __restrict__ Qh, short* __restrict__ Kh, short* __restrict__ Vth)
{
    const int t  = threadIdx.x;
    const int wv = t >> 6, l = t & 63, lg = l >> 4, li = l & 15;
    const int wr = wv >> 1, wc = wv & 1;
    const int c0g = blockIdx.x * 64, m0 = blockIdx.y * 64;
    const int sel = c0g >> 10;              // 0=q 1=k 2=v
    const int c0  = c0g & 1023;
    const float* A    = sel == 0 ? qin : (sel == 1 ? kin : vin);
    const short* Wt   = Wcat + (size_t)sel * DM * DM;
    const float* bias = sel == 0 ? bq : (sel == 1 ? bk : bv);
    short* outp       = sel == 0 ? Qh : (sel == 1 ? Kh : Vth);
    const int mode    = sel == 2 ? 2 : 1;

    __shared__ short Asl[64 * 64];
    __shared__ short Bsl[64 * 64];

    f32x4 acc[2][2] = {};
    const int sr = t >> 2, scol = (t & 3) * 16;
    const int sw = (sr & 7) << 3;

    s16x8 a0, a1;
    loadAf32(A + (size_t)(m0 + sr) * DM + scol, a0, a1);
    s16x8 b0 = *(const s16x8*)(Wt + (size_t)(c0 + sr) * DM + scol);
    s16x8 b1 = *(const s16x8*)(Wt + (size_t)(c0 + sr) * DM + scol + 8);

    for (int k0 = 0; k0 < DM; k0 += 64) {
        __syncthreads();
        *(s16x8*)&Asl[sr * 64 + (scol ^ sw)]       = a0;
        *(s16x8*)&Asl[sr * 64 + ((scol + 8) ^ sw)] = a1;
        *(s16x8*)&Bsl[sr * 64 + (scol ^ sw)]       = b0;
        *(s16x8*)&Bsl[sr * 64 + ((scol + 8) ^ sw)] = b1;
        __syncthreads();
        if (k0 + 64 < DM) {
            loadAf32(A + (size_t)(m0 + sr) * DM + k0 + 64 + scol, a0, a1);
            b0 = *(const s16x8*)(Wt + (size_t)(c0 + sr) * DM + k0 + 64 + scol);
            b1 = *(const s16x8*)(Wt + (size_t)(c0 + sr) * DM + k0 + 64 + scol + 8);
        }
        #pragma unroll
        for (int kh = 0; kh < 2; ++kh) {
            s16x8 af[2], bf[2];
            #pragma unroll
            for (int fi = 0; fi < 2; ++fi) {
                const int row = wr * 32 + fi * 16 + li;
                af[fi] = *(const s16x8*)&Asl[row * 64 + ((kh * 32 + lg * 8) ^ ((row & 7) << 3))];
            }
            #pragma unroll
            for (int fj = 0; fj < 2; ++fj) {
                const int row = wc * 32 + fj * 16 + li;
                bf[fj] = *(const s16x8*)&Bsl[row * 64 + ((kh * 32 + lg * 8) ^ ((row & 7) << 3))];
            }
            #pragma unroll
            for (int fi = 0; fi < 2; ++fi)
                #pragma unroll
                for (int fj = 0; fj < 2; ++fj)
                    acc[fi][fj] = __builtin_amdgcn_mfma_f32_16x16x32_bf16(af[fi], bf[fj], acc[fi][fj], 0, 0, 0);
        }
    }

    const int hh = c0 >> 6;
    #pragma unroll
    for (int fi = 0; fi < 2; ++fi) {
        #pragma unroll
        for (int j = 0; j < 4; ++j) {
            const int m = m0 + wr * 32 + fi * 16 + lg * 4 + j;
            const int bb = m >> 10, n = m & (NSEQ - 1);
            #pragma unroll
            for (int fj = 0; fj < 2; ++fj) {
                const int cc = wc * 32 + fj * 16 + li;
                float v = acc[fi][fj][j] + bias[c0 + cc];
                if (mode == 1)
                    outp[(((size_t)(bb * H_ + hh) * NSEQ) + n) * DKV + cc] = f2bf(v);
                else
                    outp[(((size_t)(bb * H_ + hh) * DKV) + cc) * NSEQ + n] = f2bf(v);
            }
        }
    }
}

// ---------------- out-proj GEMM: Yb = Ob @ Wto^T + bo + resid (f32 out) ----------------
__global__ __launch_bounds__(256) void gemm_out(
    const short* __restrict__ A, const short* __restrict__ Wt,
    const float* __restrict__ bias, const float* __restrict__ resid,
    float* __restrict__ outp)
{
    const int t  = threadIdx.x;
    const int wv = t >> 6, l = t & 63, lg = l >> 4, li = l & 15;
    const int wr = wv >> 1, wc = wv & 1;
    const int c0 = blockIdx.x * 64, m0 = blockIdx.y * 64;

    __shared__ short Asl[64 * 64];
    __shared__ short Bsl[64 * 64];

    f32x4 acc[2][2] = {};
    const int sr = t >> 2, scol = (t & 3) * 16;
    const int sw = (sr & 7) << 3;

    s16x8 a0 = *(const s16x8*)(A + (size_t)(m0 + sr) * DM + scol);
    s16x8 a1 = *(const s16x8*)(A + (size_t)(m0 + sr) * DM + scol + 8);
    s16x8 b0 = *(const s16x8*)(Wt + (size_t)(c0 + sr) * DM + scol);
    s16x8 b1 = *(const s16x8*)(Wt + (size_t)(c0 + sr) * DM + scol + 8);

    for (int k0 = 0; k0 < DM; k0 += 64) {
        __syncthreads();
        *(s16x8*)&Asl[sr * 64 + (scol ^ sw)]       = a0;
        *(s16x8*)&Asl[sr * 64 + ((scol + 8) ^ sw)] = a1;
        *(s16x8*)&Bsl[sr * 64 + (scol ^ sw)]       = b0;
        *(s16x8*)&Bsl[sr * 64 + ((scol + 8) ^ sw)] = b1;
        __syncthreads();
        if (k0 + 64 < DM) {
            a0 = *(const s16x8*)(A + (size_t)(m0 + sr) * DM + k0 + 64 + scol);
            a1 = *(const s16x8*)(A + (size_t)(m0 + sr) * DM + k0 + 64 + scol + 8);
            b0 = *(const s16x8*)(Wt + (size_t)(c0 + sr) * DM + k0 + 64 + scol);
            b1 = *(const s16x8*)(Wt + (size_t)(c0 + sr) * DM + k0 + 64 + scol + 8);
        }
        #pragma unroll
        for (int kh = 0; kh < 2; ++kh) {
            s16x8 af[2], bf[2];
            #pragma unroll
            for (int fi = 0; fi < 2; ++fi) {
                const int row = wr * 32 + fi * 16 + li;
                af[fi] = *(const s16x8*)&Asl[row * 64 + ((kh * 32 + lg * 8) ^ ((row & 7) << 3))];
            }
            #pragma unroll
            for (int fj = 0; fj < 2; ++fj) {
                const int row = wc * 32 + fj * 16 + li;
                bf[fj] = *(const s16x8*)&Bsl[row * 64 + ((kh * 32 + lg * 8) ^ ((row & 7) << 3))];
            }
            #pragma unroll
            for (int fi = 0; fi < 2; ++fi)
                #pragma unroll
                for (int fj = 0; fj < 2; ++fj)
                    acc[fi][fj] = __builtin_amdgcn_mfma_f32_16x16x32_bf16(af[fi], bf[fj], acc[fi][fj], 0, 0, 0);
        }
    }

    #pragma unroll
    for (int fi = 0; fi < 2; ++fi) {
        #pragma unroll
        for (int j = 0; j < 4; ++j) {
            const int m = m0 + wr * 32 + fi * 16 + lg * 4 + j;
            #pragma unroll
            for (int fj = 0; fj < 2; ++fj) {
                const int c = c0 + wc * 32 + fj * 16 + li;
                outp[(size_t)m * DM + c] = acc[fi][fj][j] + bias[c] + resid[(size_t)m * DM + c];
            }
        }
    }
}

// ---------------- flash attention, NSPLIT=16, async-LDS staging, Plds aliased on Wl ----
// Round-14: async burst lifted BW 1.5->2.0 TB/s; occupancy (3 blocks/CU @ 47KB LDS)
// is now binding. This round: Wl (wgt LDS) is dead after the sv-loop; P writes start
// after it -> alias Plds onto Wl (one extra barrier). LDS 47->36.8KB -> 4 blocks/CU.
__global__ __launch_bounds__(256) void attn_one(
    const short* __restrict__ Qb, const short* __restrict__ Kb, const short* __restrict__ Vt,
    const void* __restrict__ mask, const float* __restrict__ wgt,
    const int* __restrict__ flagp, short* __restrict__ Opart,
    float* __restrict__ mpart, float* __restrict__ lpart)
{
    const int t  = threadIdx.x;
    const int wv = t >> 6;
    const int l  = t & 63;
    const int lg = l >> 4;
    const int li = l & 15;
    const int qt = blockIdx.x >> 4;          // 0..15
    const int sp = blockIdx.x & (NSPLIT-1);  // 0..15
    const int h  = blockIdx.y, b = blockIdx.z;
    const size_t bh = (size_t)b * H_ + h;
    const int qrow = qt*64 + wv*16 + li;     // softmax-layout row
    const int kc = sp * 64;

    // fragment-linear LDS: frag f at [f*frag_elems], lane l at +l*(16B or 4B)
    __shared__ short Kl[8 * 512];            // 8 KB : frag (dc*4+nt), lane 16B
    __shared__ short Vl[8 * 512];            // 8 KB : frag (kch*4+dt), lane 16B
    __shared__ float Wl[16 * 256];           // 16 KB: frag (nt*4+wv), lane 16B; Plds alias after sv
    __shared__ unsigned char Ml[16 * 256];   // 4 KB : frag (nt*4+wv), lane 4B
    short* Plds = (short*)Wl;                // per-wave P tile [4][16][80] (10KB < 16KB)

    const short* Qp = Qb + (bh * NSEQ + qt*64 + wv*16) * DKV;
    const short* Kp = Kb + bh * NSEQ * DKV;
    const short* Vp = Vt + bh * DKV * NSEQ;
    const size_t moff = (bh * NSEQ + qrow) * NSEQ;
    const size_t rowT = bh * NSEQ + (size_t)qt * 64;       // tile row base in wgt/mask
    const int mmode = *flagp;
    const unsigned* Mi = (const unsigned*)mask;
    const unsigned char* Mb = (const unsigned char*)mask;

    // ---- async staging burst: 48 x global_load_lds, zero VGPR cost ----
    if (wv == 0) {
        #pragma unroll
        for (int i = 0; i < 8; ++i) {        // K frag i = dc*4+nt
            const int nt = i & 3, dc = i >> 2;
            gll16(Kp + (size_t)(kc + nt*16 + li) * DKV + dc*32 + lg*8, Kl + i*512);
        }
        #pragma unroll
        for (int j = 0; j < 4; ++j)
            gll4(Mb + (rowT + (j&3)*16 + li) * NSEQ + kc + (j>>2)*16 + lg*4, Ml + j*256);
    } else if (wv == 1) {
        #pragma unroll
        for (int i = 0; i < 8; ++i) {        // V frag i = kch*4+dt
            const int dt = i & 3, kch = i >> 2;
            gll16(Vp + (size_t)(dt*16 + li) * NSEQ + kc + kch*32 + lg*8, Vl + i*512);
        }
        #pragma unroll
        for (int j = 4; j < 8; ++j)
            gll4(Mb + (rowT + (j&3)*16 + li) * NSEQ + kc + (j>>2)*16 + lg*4, Ml + j*256);
    } else if (wv == 2) {
        #pragma unroll
        for (int j = 0; j < 8; ++j)
            gll16(wgt + (rowT + (j&3)*16 + li) * NSEQ + kc + (j>>2)*16 + lg*4, Wl + j*256);
        #pragma unroll
        for (int j = 8; j < 12; ++j)
            gll4(Mb + (rowT + (j&3)*16 + li) * NSEQ + kc + (j>>2)*16 + lg*4, Ml + j*256);
    } else {
        #pragma unroll
        for (int j = 8; j < 16; ++j)
            gll16(wgt + (rowT + (j&3)*16 + li) * NSEQ + kc + (j>>2)*16 + lg*4, Wl + j*256);
        #pragma unroll
        for (int j = 12; j < 16; ++j)
            gll4(Mb + (rowT + (j&3)*16 + li) * NSEQ + kc + (j>>2)*16 + lg*4, Ml + j*256);
    }

    // Q fragments (tiny; L2/L3-resident)
    s16x8 qa[2];
    qa[0] = *(const s16x8*)(Qp + (size_t)li * DKV + lg*8);
    qa[1] = *(const s16x8*)(Qp + (size_t)li * DKV + 32 + lg*8);

    SYNC_STAGE;

    // ---- S^T = K * Q^T : sc[nt][r] = S[q=li][key = kc + nt*16 + lg*4 + r] ----
    f32x4 sc[4] = {};
    #pragma unroll
    for (int dc = 0; dc < 2; ++dc)
        #pragma unroll
        for (int nt = 0; nt < 4; ++nt) {
            s16x8 kb = *(const s16x8*)&Kl[(dc*4 + nt)*512 + l*8];
            sc[nt] = __builtin_amdgcn_mfma_f32_16x16x32_bf16(kb, qa[dc], sc[nt], 0, 0, 0);
        }

    // ---- single-pass softmax; wgt/mask from LDS (Wl/Ml live here) ----
    float sv[16];
    float cmax = -1e30f;
    #pragma unroll
    for (int nt = 0; nt < 4; ++nt) {
        f32x4 w4 = *(const f32x4*)&Wl[(nt*4 + wv)*256 + l*4];
        unsigned mm[4];
        if (mmode) {
            unsigned u = *(const unsigned*)&Ml[(nt*4 + wv)*256 + l*4];
            mm[0] = u & 0xffu; mm[1] = (u >> 8) & 0xffu;
            mm[2] = (u >> 16) & 0xffu; mm[3] = u >> 24;
        } else {
            u32x4 mi = *(const u32x4*)(Mi + moff + kc + nt*16 + lg*4);
            mm[0] = mi[0]; mm[1] = mi[1]; mm[2] = mi[2]; mm[3] = mi[3];
        }
        #pragma unroll
        for (int r = 0; r < 4; ++r) {
            float s = sc[nt][r] * 0.125f * w4[r];
            s = mm[r] ? -1e30f : s;
            sv[nt*4 + r] = s;
            cmax = fmaxf(cmax, s);
        }
    }
    cmax = fmaxf(cmax, __shfl_xor(cmax, 16));
    cmax = fmaxf(cmax, __shfl_xor(cmax, 32));

    __syncthreads();   // Wl fully consumed by ALL waves before Plds overwrites it

    float csum = 0.f;
    #pragma unroll
    for (int nt = 0; nt < 4; ++nt) {
        float p0 = __expf(sv[nt*4+0] - cmax), p1 = __expf(sv[nt*4+1] - cmax);
        float p2 = __expf(sv[nt*4+2] - cmax), p3 = __expf(sv[nt*4+3] - cmax);
        csum += p0 + p1 + p2 + p3;
        unsigned u0 = (unsigned short)f2bf(p0) | ((unsigned)(unsigned short)f2bf(p1) << 16);
        unsigned u1 = (unsigned short)f2bf(p2) | ((unsigned)(unsigned short)f2bf(p3) << 16);
        uint2 pk; pk.x = u0; pk.y = u1;
        *(uint2*)&Plds[wv*1280 + li*80 + nt*16 + lg*4] = pk;
    }
    csum += __shfl_xor(csum, 16);
    csum += __shfl_xor(csum, 32);

    // ---- PV from LDS V fragments ----
    f32x4 oacc[4] = {};
    #pragma unroll
    for (int kch = 0; kch < 2; ++kch) {
        s16x8 pa = *(const s16x8*)&Plds[wv*1280 + li*80 + kch*32 + lg*8];
        #pragma unroll
        for (int dt = 0; dt < 4; ++dt) {
            s16x8 vb = *(const s16x8*)&Vl[(kch*4 + dt)*512 + l*8];
            oacc[dt] = __builtin_amdgcn_mfma_f32_16x16x32_bf16(pa, vb, oacc[dt], 0, 0, 0);
        }
    }

    // ---- write partials ----
    const size_t SBH = (size_t)B_ * H_ * NSEQ;
    if (lg == 0) {
        mpart[(size_t)sp * SBH + bh * NSEQ + qrow] = cmax;
        lpart[(size_t)sp * SBH + bh * NSEQ + qrow] = csum;
    }
    #pragma unroll
    for (int dt = 0; dt < 4; ++dt)
        #pragma unroll
        for (int r = 0; r < 4; ++r)
            Opart[((size_t)sp * SBH + bh * NSEQ + qt*64 + wv*16 + lg*4 + r) * DKV + dt*16 + li]
                = f2bf(oacc[dt][r]);
}

// ---------------- split combine: merge 16 partials, normalize ----------------
__global__ __launch_bounds__(256, 1) void attn_combine(
    const short* __restrict__ Opart, const float* __restrict__ mpart,
    const float* __restrict__ lpart, short* __restrict__ Ob)
{
    const size_t SBH = (size_t)B_ * H_ * NSEQ;
    const int R = blockIdx.x * 4 + (threadIdx.x >> 6);
    const int d = threadIdx.x & 63;
    const int bh = R >> 10, n = R & (NSEQ - 1);
    const int b = bh >> 4, h = bh & (H_ - 1);

    float ms[NSPLIT], ls[NSPLIT], ov[NSPLIT];
    #pragma unroll
    for (int s = 0; s < NSPLIT; ++s) {
        ms[s] = mpart[(size_t)s * SBH + R];
        ls[s] = lpart[(size_t)s * SBH + R];
        ov[s] = bf2f(Opart[((size_t)s * SBH + R) * DKV + d]);
    }
    float mstar = -1e30f;
    #pragma unroll
    for (int s = 0; s < NSPLIT; ++s) mstar = fmaxf(mstar, ms[s]);
    float lstar = 0.f, acc = 0.f;
    #pragma unroll
    for (int s = 0; s < NSPLIT; ++s) {
        float w = __expf(ms[s] - mstar);
        lstar += w * ls[s];
        acc   += w * ov[s];
    }
    Ob[((size_t)b * NSEQ + n) * DM + h * DKV + d] = f2bf(acc / lstar);
}

// ---------------- residual + LayerNorm ----------------
__global__ __launch_bounds__(256) void ln_kernel(
    const float* __restrict__ Y, const float* __restrict__ gamma,
    const float* __restrict__ beta, float* __restrict__ out)
{
    const int row = blockIdx.x;
    const int t = threadIdx.x;
    const float* y = Y + (size_t)row * DM;
    float4 x = *(const float4*)(y + t*4);
    __shared__ float red[4];
    float s = x.x + x.y + x.z + x.w;
    #pragma unroll
    for (int off = 32; off > 0; off >>= 1) s += __shfl_xor(s, off);
    if ((t & 63) == 0) red[t >> 6] = s;
    __syncthreads();
    float mean = (red[0]+red[1]+red[2]+red[3]) * (1.0f/DM);
    float d0 = x.x-mean, d1 = x.y-mean, d2 = x.z-mean, d3 = x.w-mean;
    float sq = d0*d0 + d1*d1 + d2*d2 + d3*d3;
    __syncthreads();
    #pragma unroll
    for (int off = 32; off > 0; off >>= 1) sq += __shfl_xor(sq, off);
    if ((t & 63) == 0) red[t >> 6] = sq;
    __syncthreads();
    float var = (red[0]+red[1]+red[2]+red[3]) * (1.0f/DM);
    float rstd = rsqrtf(var + LNEPS);
    int c = t * 4;
    float4 g  = *(const float4*)(gamma + c);
    float4 bb = *(const float4*)(beta + c);
    float4 o;
    o.x = d0*rstd*g.x + bb.x;
    o.y = d1*rstd*g.y + bb.y;
    o.z = d2*rstd*g.z + bb.z;
    o.w = d3*rstd*g.w + bb.w;
    *(float4*)(out + (size_t)row*DM + c) = o;
}

extern "C" void kernel_launch(void* const* d_in, const int* in_sizes, int n_in,
                              void* d_out, int out_size, void* d_ws, size_t ws_size,
                              hipStream_t stream)
{
    const float* queries = (const float*)d_in[0];
    const float* keys    = (const float*)d_in[1];
    const float* values  = (const float*)d_in[2];
    const void*  mask    = d_in[3];
    const float* wgt     = (const float*)d_in[4];
    const float* Wq = (const float*)d_in[5];  const float* bq = (const float*)d_in[6];
    const float* Wk = (const float*)d_in[7];  const float* bk = (const float*)d_in[8];
    const float* Wv = (const float*)d_in[9];  const float* bv = (const float*)d_in[10];
    const float* Wo = (const float*)d_in[11]; const float* bo = (const float*)d_in[12];
    const float* gamma = (const float*)d_in[13]; const float* beta = (const float*)d_in[14];
    float* out = (float*)d_out;

    const size_t SZ  = (size_t)B_ * NSEQ * DM;     // 2M elements
    const size_t WSZ = (size_t)DM * DM;            // 1M elements
    const size_t SBH = (size_t)B_ * H_ * NSEQ;     // 32K rows

    char* ws = (char*)d_ws;
    int*   flag = (int*)ws;
    short* Wtq = (short*)(ws + 256);               // Wtq|Wtk|Wtv contiguous = Wcat
    short* Wtk = Wtq + WSZ;
    short* Wtv = Wtk + WSZ;
    short* Wto = Wtv + WSZ;
    short* Qh  = Wto + WSZ;
    short* Kh  = Qh + SZ;
    short* Vth = Kh + SZ;
    short* Opart = Vth + SZ;                       // 16 x 4 MB bf16
    float* mpart = (float*)(Opart + (size_t)NSPLIT * SBH * DKV);
    float* lpart = mpart + NSPLIT * SBH;
    short* Ob  = (short*)(lpart + NSPLIT * SBH);
    float* Yb  = (float*)Opart;                    // alias: Opart dead after combine

    detect_mask<<<1, 1, 0, stream>>>((const unsigned*)mask, flag);
    castT4_bf16<<<dim3(32, 32, 4), 256, 0, stream>>>(Wq, Wk, Wv, Wo, Wtq, Wtk, Wtv, Wto);

    gemm_qkv<<<dim3(48, 32), 256, 0, stream>>>(queries, keys, values, Wtq,
                                               bq, bk, bv, Qh, Kh, Vth);

    attn_one<<<dim3(16 * NSPLIT, H_, B_), 256, 0, stream>>>(
        Qh, Kh, Vth, mask, wgt, flag, Opart, mpart, lpart);
    attn_combine<<<dim3((int)(SBH / 4)), 256, 0, stream>>>(Opart, mpart, lpart, Ob);

    gemm_out<<<dim3(16, 32), 256, 0, stream>>>(Ob, Wto, bo, queries, Yb);
    ln_kernel<<<dim3(B_*NSEQ), 256, 0, stream>>>(Yb, gamma, beta, out);
}

// Round 16
// 206.842 us; speedup vs baseline: 1.0702x; 1.0702x over previous
//
#include <hip/hip_runtime.h>
#include <hip/hip_bf16.h>
#include <math.h>

#define B_   2
#define H_   16
#define NSEQ 1024
#define DM   1024
#define DKV  64
#define NSPLIT 16
#define LNEPS 1e-5f

typedef __attribute__((ext_vector_type(8))) short s16x8;
typedef __attribute__((ext_vector_type(4))) float f32x4;
typedef __attribute__((ext_vector_type(4))) unsigned u32x4;

__device__ inline short f2bf(float f) {
    __hip_bfloat16 h = __float2bfloat16(f);
    return *reinterpret_cast<short*>(&h);
}
__device__ inline float bf2f(short s) {
    unsigned u = ((unsigned)(unsigned short)s) << 16;
    return __uint_as_float(u);
}

// async global->LDS; LDS dest = wave-uniform base + lane*width; global src per-lane.
__device__ __forceinline__ void gll16(const void* g, void* l) {
    __builtin_amdgcn_global_load_lds(
        (const __attribute__((address_space(1))) unsigned int*)g,
        (__attribute__((address_space(3))) unsigned int*)l, 16, 0, 0);
}
__device__ __forceinline__ void gll4(const void* g, void* l) {
    __builtin_amdgcn_global_load_lds(
        (const __attribute__((address_space(1))) unsigned int*)g,
        (__attribute__((address_space(3))) unsigned int*)l, 4, 0, 0);
}

#define SYNC_STAGE do { asm volatile("s_waitcnt vmcnt(0)" ::: "memory"); __syncthreads(); } while (0)

// ---------------- mask dtype detection ----------------
__global__ void detect_mask(const unsigned* __restrict__ mask_words, int* __restrict__ flag) {
    unsigned f = 0;
    for (int i = 0; i < 256; ++i) f |= (mask_words[i] > 1u) ? 1u : 0u;
    *flag = (int)f;   // 1 => packed uint8 bools, 0 => int32 0/1
}

// ---------------- W[K][N] f32 -> Wt[N][K] bf16 (4 weights in one launch) ----------------
__global__ __launch_bounds__(256) void castT4_bf16(
    const float* __restrict__ w0, const float* __restrict__ w1,
    const float* __restrict__ w2, const float* __restrict__ w3,
    short* __restrict__ t0, short* __restrict__ t1,
    short* __restrict__ t2, short* __restrict__ t3) {
    const float* W = blockIdx.z == 0 ? w0 : (blockIdx.z == 1 ? w1 : (blockIdx.z == 2 ? w2 : w3));
    short* Wt      = blockIdx.z == 0 ? t0 : (blockIdx.z == 1 ? t1 : (blockIdx.z == 2 ? t2 : t3));
    __shared__ float tl[32][33];
    const int k0 = blockIdx.y * 32, n0 = blockIdx.x * 32;
    const int r = threadIdx.x >> 3, c4 = (threadIdx.x & 7) * 4;
    *(float4*)&tl[r][c4] = *(const float4*)(W + (size_t)(k0 + r) * DM + n0 + c4);
    __syncthreads();
    unsigned u0 = (unsigned short)f2bf(tl[c4+0][r]) | ((unsigned)(unsigned short)f2bf(tl[c4+1][r]) << 16);
    unsigned u1 = (unsigned short)f2bf(tl[c4+2][r]) | ((unsigned)(unsigned short)f2bf(tl[c4+3][r]) << 16);
    uint2 pk; pk.x = u0; pk.y = u1;
    *(uint2*)(Wt + (size_t)(n0 + r) * DM + k0 + c4) = pk;
}

// ---------------- shared GEMM core pieces ----------------
__device__ inline void loadAf32(const float* p, s16x8& a0, s16x8& a1) {
    f32x4 v0 = *(const f32x4*)p,       v1 = *(const f32x4*)(p + 4);
    f32x4 v2 = *(const f32x4*)(p + 8), v3 = *(const f32x4*)(p + 12);
    a0[0]=f2bf(v0[0]); a0[1]=f2bf(v0[1]); a0[2]=f2bf(v0[2]); a0[3]=f2bf(v0[3]);
    a0[4]=f2bf(v1[0]); a0[5]=f2bf(v1[1]); a0[6]=f2bf(v1[2]); a0[7]=f2bf(v1[3]);
    a1[0]=f2bf(v2[0]); a1[1]=f2bf(v2[1]); a1[2]=f2bf(v2[2]); a1[3]=f2bf(v2[3]);
    a1[4]=f2bf(v3[0]); a1[5]=f2bf(v3[1]); a1[6]=f2bf(v3[2]); a1[7]=f2bf(v3[3]);
}

// ---------------- fused QKV projection: 3 GEMMs in one launch ----------------
__global__ __launch_bounds__(256) void gemm_qkv(
    const float* __restrict__ qin, const float* __restrict__ kin, const float* __restrict__ vin,
    const short* __restrict__ Wcat,     // Wtq|Wtk|Wtv contiguous, each [DM][DM]
    const float* __restrict__ bq, const float* __restrict__ bk, const float* __restrict__ bv,
    short* __restrict__ Qh, short* __restrict__ Kh, short* __restrict__ Vth)
{
    const int t  = threadIdx.x;
    const int wv = t >> 6, l = t & 63, lg = l >> 4, li = l & 15;
    const int wr = wv >> 1, wc = wv & 1;
    const int c0g = blockIdx.x * 64, m0 = blockIdx.y * 64;
    const int sel = c0g >> 10;              // 0=q 1=k 2=v
    const int c0  = c0g & 1023;
    const float* A    = sel == 0 ? qin : (sel == 1 ? kin : vin);
    const short* Wt   = Wcat + (size_t)sel * DM * DM;
    const float* bias = sel == 0 ? bq : (sel == 1 ? bk : bv);
    short* outp       = sel == 0 ? Qh : (sel == 1 ? Kh : Vth);
    const int mode    = sel == 2 ? 2 : 1;

    __shared__ short Asl[64 * 64];
    __shared__ short Bsl[64 * 64];

    f32x4 acc[2][2] = {};
    const int sr = t >> 2, scol = (t & 3) * 16;
    const int sw = (sr & 7) << 3;

    s16x8 a0, a1;
    loadAf32(A + (size_t)(m0 + sr) * DM + scol, a0, a1);
    s16x8 b0 = *(const s16x8*)(Wt + (size_t)(c0 + sr) * DM + scol);
    s16x8 b1 = *(const s16x8*)(Wt + (size_t)(c0 + sr) * DM + scol + 8);

    for (int k0 = 0; k0 < DM; k0 += 64) {
        __syncthreads();
        *(s16x8*)&Asl[sr * 64 + (scol ^ sw)]       = a0;
        *(s16x8*)&Asl[sr * 64 + ((scol + 8) ^ sw)] = a1;
        *(s16x8*)&Bsl[sr * 64 + (scol ^ sw)]       = b0;
        *(s16x8*)&Bsl[sr * 64 + ((scol + 8) ^ sw)] = b1;
        __syncthreads();
        if (k0 + 64 < DM) {
            loadAf32(A + (size_t)(m0 + sr) * DM + k0 + 64 + scol, a0, a1);
            b0 = *(const s16x8*)(Wt + (size_t)(c0 + sr) * DM + k0 + 64 + scol);
            b1 = *(const s16x8*)(Wt + (size_t)(c0 + sr) * DM + k0 + 64 + scol + 8);
        }
        #pragma unroll
        for (int kh = 0; kh < 2; ++kh) {
            s16x8 af[2], bf[2];
            #pragma unroll
            for (int fi = 0; fi < 2; ++fi) {
                const int row = wr * 32 + fi * 16 + li;
                af[fi] = *(const s16x8*)&Asl[row * 64 + ((kh * 32 + lg * 8) ^ ((row & 7) << 3))];
            }
            #pragma unroll
            for (int fj = 0; fj < 2; ++fj) {
                const int row = wc * 32 + fj * 16 + li;
                bf[fj] = *(const s16x8*)&Bsl[row * 64 + ((kh * 32 + lg * 8) ^ ((row & 7) << 3))];
            }
            #pragma unroll
            for (int fi = 0; fi < 2; ++fi)
                #pragma unroll
                for (int fj = 0; fj < 2; ++fj)
                    acc[fi][fj] = __builtin_amdgcn_mfma_f32_16x16x32_bf16(af[fi], bf[fj], acc[fi][fj], 0, 0, 0);
        }
    }

    const int hh = c0 >> 6;
    #pragma unroll
    for (int fi = 0; fi < 2; ++fi) {
        #pragma unroll
        for (int j = 0; j < 4; ++j) {
            const int m = m0 + wr * 32 + fi * 16 + lg * 4 + j;
            const int bb = m >> 10, n = m & (NSEQ - 1);
            #pragma unroll
            for (int fj = 0; fj < 2; ++fj) {
                const int cc = wc * 32 + fj * 16 + li;
                float v = acc[fi][fj][j] + bias[c0 + cc];
                if (mode == 1)
                    outp[(((size_t)(bb * H_ + hh) * NSEQ) + n) * DKV + cc] = f2bf(v);
                else
                    outp[(((size_t)(bb * H_ + hh) * DKV) + cc) * NSEQ + n] = f2bf(v);
            }
        }
    }
}

// ---------------- out-proj GEMM: Yb = Ob @ Wto^T + bo + resid (f32 out) ----------------
__global__ __launch_bounds__(256) void gemm_out(
    const short* __restrict__ A, const short* __restrict__ Wt,
    const float* __restrict__ bias, const float* __restrict__ resid,
    float* __restrict__ outp)
{
    const int t  = threadIdx.x;
    const int wv = t >> 6, l = t & 63, lg = l >> 4, li = l & 15;
    const int wr = wv >> 1, wc = wv & 1;
    const int c0 = blockIdx.x * 64, m0 = blockIdx.y * 64;

    __shared__ short Asl[64 * 64];
    __shared__ short Bsl[64 * 64];

    f32x4 acc[2][2] = {};
    const int sr = t >> 2, scol = (t & 3) * 16;
    const int sw = (sr & 7) << 3;

    s16x8 a0 = *(const s16x8*)(A + (size_t)(m0 + sr) * DM + scol);
    s16x8 a1 = *(const s16x8*)(A + (size_t)(m0 + sr) * DM + scol + 8);
    s16x8 b0 = *(const s16x8*)(Wt + (size_t)(c0 + sr) * DM + scol);
    s16x8 b1 = *(const s16x8*)(Wt + (size_t)(c0 + sr) * DM + scol + 8);

    for (int k0 = 0; k0 < DM; k0 += 64) {
        __syncthreads();
        *(s16x8*)&Asl[sr * 64 + (scol ^ sw)]       = a0;
        *(s16x8*)&Asl[sr * 64 + ((scol + 8) ^ sw)] = a1;
        *(s16x8*)&Bsl[sr * 64 + (scol ^ sw)]       = b0;
        *(s16x8*)&Bsl[sr * 64 + ((scol + 8) ^ sw)] = b1;
        __syncthreads();
        if (k0 + 64 < DM) {
            a0 = *(const s16x8*)(A + (size_t)(m0 + sr) * DM + k0 + 64 + scol);
            a1 = *(const s16x8*)(A + (size_t)(m0 + sr) * DM + k0 + 64 + scol + 8);
            b0 = *(const s16x8*)(Wt + (size_t)(c0 + sr) * DM + k0 + 64 + scol);
            b1 = *(const s16x8*)(Wt + (size_t)(c0 + sr) * DM + k0 + 64 + scol + 8);
        }
        #pragma unroll
        for (int kh = 0; kh < 2; ++kh) {
            s16x8 af[2], bf[2];
            #pragma unroll
            for (int fi = 0; fi < 2; ++fi) {
                const int row = wr * 32 + fi * 16 + li;
                af[fi] = *(const s16x8*)&Asl[row * 64 + ((kh * 32 + lg * 8) ^ ((row & 7) << 3))];
            }
            #pragma unroll
            for (int fj = 0; fj < 2; ++fj) {
                const int row = wc * 32 + fj * 16 + li;
                bf[fj] = *(const s16x8*)&Bsl[row * 64 + ((kh * 32 + lg * 8) ^ ((row & 7) << 3))];
            }
            #pragma unroll
            for (int fi = 0; fi < 2; ++fi)
                #pragma unroll
                for (int fj = 0; fj < 2; ++fj)
                    acc[fi][fj] = __builtin_amdgcn_mfma_f32_16x16x32_bf16(af[fi], bf[fj], acc[fi][fj], 0, 0, 0);
        }
    }

    #pragma unroll
    for (int fi = 0; fi < 2; ++fi) {
        #pragma unroll
        for (int j = 0; j < 4; ++j) {
            const int m = m0 + wr * 32 + fi * 16 + lg * 4 + j;
            #pragma unroll
            for (int fj = 0; fj < 2; ++fj) {
                const int c = c0 + wc * 32 + fj * 16 + li;
                outp[(size_t)m * DM + c] = acc[fi][fj][j] + bias[c] + resid[(size_t)m * DM + c];
            }
        }
    }
}

// ---------------- flash attention, NSPLIT=16, async-LDS staging, row-contiguous wgt/mask ----
// Round-15: occupancy lever dead (38% occ, same 126us/2.0TB/s). New theory: DRAM channel/
// page locality. Old wgt staging read 16 rows x 64B at 4KB stride per instr (stride-4096
// keeps channel-select bits constant -> few channels hammered). New mapping: each instr
// covers 4 consecutive rows x full 64-col width -> wgt 256B runs, mask 64B full-row runs.
// XOR involution (chunk ^= row&3) on BOTH global source and LDS read (rule 21) keeps the
// softmax-side LDS reads ~4-way max. Same bytes, same instr count, same LDS size.
__global__ __launch_bounds__(256) void attn_one(
    const short* __restrict__ Qb, const short* __restrict__ Kb, const short* __restrict__ Vt,
    const void* __restrict__ mask, const float* __restrict__ wgt,
    const int* __restrict__ flagp, short* __restrict__ Opart,
    float* __restrict__ mpart, float* __restrict__ lpart)
{
    const int t  = threadIdx.x;
    const int wv = t >> 6;
    const int l  = t & 63;
    const int lg = l >> 4;
    const int li = l & 15;
    const int qt = blockIdx.x >> 4;          // 0..15
    const int sp = blockIdx.x & (NSPLIT-1);  // 0..15
    const int h  = blockIdx.y, b = blockIdx.z;
    const size_t bh = (size_t)b * H_ + h;
    const int qrow = qt*64 + wv*16 + li;     // softmax-layout row
    const int kc = sp * 64;

    __shared__ short Kl[8 * 512];            // 8 KB : frag (dc*4+nt), lane 16B
    __shared__ short Vl[8 * 512];            // 8 KB : frag (kch*4+dt), lane 16B
    __shared__ float Wl[16 * 256];           // 16 KB: instr j = rows 4j..4j+3, swizzled chunks
    __shared__ unsigned char Ml[16 * 256];   // 4 KB : same row-block layout
    short* Plds = (short*)Wl;                // P tile alias after Wl consumed

    const short* Qp = Qb + (bh * NSEQ + qt*64 + wv*16) * DKV;
    const short* Kp = Kb + bh * NSEQ * DKV;
    const short* Vp = Vt + bh * DKV * NSEQ;
    const size_t moff = (bh * NSEQ + qrow) * NSEQ;
    const size_t rowT = bh * NSEQ + (size_t)qt * 64;       // tile row base in wgt/mask
    const int mmode = *flagp;
    const unsigned* Mi = (const unsigned*)mask;
    const unsigned char* Mb = (const unsigned char*)mask;

    // per-lane source mapping for wgt/mask staging: instr j covers rows 4j..4j+3;
    // lane l -> row 4j + (l>>4), 16B/4B chunk ((l&15) ^ (l>>4))  [XOR involution]
    const int srow = l >> 4;                  // 0..3 sub-row
    const int schk = (l & 15) ^ srow;         // swizzled chunk

    if (wv == 0) {
        #pragma unroll
        for (int i = 0; i < 8; ++i) {        // K frag i = dc*4+nt (unchanged)
            const int nt = i & 3, dc = i >> 2;
            gll16(Kp + (size_t)(kc + nt*16 + li) * DKV + dc*32 + lg*8, Kl + i*512);
        }
        #pragma unroll
        for (int j = 0; j < 4; ++j)
            gll4(Mb + (rowT + j*4 + srow) * NSEQ + kc + schk*4, Ml + j*256);
    } else if (wv == 1) {
        #pragma unroll
        for (int i = 0; i < 8; ++i) {        // V frag i = kch*4+dt (unchanged)
            const int dt = i & 3, kch = i >> 2;
            gll16(Vp + (size_t)(dt*16 + li) * NSEQ + kc + kch*32 + lg*8, Vl + i*512);
        }
        #pragma unroll
        for (int j = 4; j < 8; ++j)
            gll4(Mb + (rowT + j*4 + srow) * NSEQ + kc + schk*4, Ml + j*256);
    } else if (wv == 2) {
        #pragma unroll
        for (int j = 0; j < 8; ++j)
            gll16(wgt + (rowT + j*4 + srow) * NSEQ + kc + schk*4, Wl + j*256);
        #pragma unroll
        for (int j = 8; j < 12; ++j)
            gll4(Mb + (rowT + j*4 + srow) * NSEQ + kc + schk*4, Ml + j*256);
    } else {
        #pragma unroll
        for (int j = 8; j < 16; ++j)
            gll16(wgt + (rowT + j*4 + srow) * NSEQ + kc + schk*4, Wl + j*256);
        #pragma unroll
        for (int j = 12; j < 16; ++j)
            gll4(Mb + (rowT + j*4 + srow) * NSEQ + kc + schk*4, Ml + j*256);
    }

    // Q fragments (tiny; L2/L3-resident)
    s16x8 qa[2];
    qa[0] = *(const s16x8*)(Qp + (size_t)li * DKV + lg*8);
    qa[1] = *(const s16x8*)(Qp + (size_t)li * DKV + 32 + lg*8);

    SYNC_STAGE;

    // ---- S^T = K * Q^T : sc[nt][r] = S[q=li][key = kc + nt*16 + lg*4 + r] ----
    f32x4 sc[4] = {};
    #pragma unroll
    for (int dc = 0; dc < 2; ++dc)
        #pragma unroll
        for (int nt = 0; nt < 4; ++nt) {
            s16x8 kb = *(const s16x8*)&Kl[(dc*4 + nt)*512 + l*8];
            sc[nt] = __builtin_amdgcn_mfma_f32_16x16x32_bf16(kb, qa[dc], sc[nt], 0, 0, 0);
        }

    // ---- single-pass softmax; wgt/mask from row-block LDS layout ----
    // R = wv*16+li: block (R>>2) = wv*4 + (li>>2), sub-row rs = li&3;
    // chunk cg = nt*4+lg stored at position cg^rs (involution).
    const int rq = li >> 2, rs = li & 3;
    float sv[16];
    float cmax = -1e30f;
    #pragma unroll
    for (int nt = 0; nt < 4; ++nt) {
        const int pos = ((nt*4 + lg) ^ rs) * 4;
        f32x4 w4 = *(const f32x4*)&Wl[(wv*4 + rq)*256 + rs*64 + pos];
        unsigned mm[4];
        if (mmode) {
            unsigned u = *(const unsigned*)&Ml[(wv*4 + rq)*256 + rs*64 + pos];
            mm[0] = u & 0xffu; mm[1] = (u >> 8) & 0xffu;
            mm[2] = (u >> 16) & 0xffu; mm[3] = u >> 24;
        } else {
            u32x4 mi = *(const u32x4*)(Mi + moff + kc + nt*16 + lg*4);
            mm[0] = mi[0]; mm[1] = mi[1]; mm[2] = mi[2]; mm[3] = mi[3];
        }
        #pragma unroll
        for (int r = 0; r < 4; ++r) {
            float s = sc[nt][r] * 0.125f * w4[r];
            s = mm[r] ? -1e30f : s;
            sv[nt*4 + r] = s;
            cmax = fmaxf(cmax, s);
        }
    }
    cmax = fmaxf(cmax, __shfl_xor(cmax, 16));
    cmax = fmaxf(cmax, __shfl_xor(cmax, 32));

    __syncthreads();   // Wl fully consumed by ALL waves before Plds overwrites it

    float csum = 0.f;
    #pragma unroll
    for (int nt = 0; nt < 4; ++nt) {
        float p0 = __expf(sv[nt*4+0] - cmax), p1 = __expf(sv[nt*4+1] - cmax);
        float p2 = __expf(sv[nt*4+2] - cmax), p3 = __expf(sv[nt*4+3] - cmax);
        csum += p0 + p1 + p2 + p3;
        unsigned u0 = (unsigned short)f2bf(p0) | ((unsigned)(unsigned short)f2bf(p1) << 16);
        unsigned u1 = (unsigned short)f2bf(p2) | ((unsigned)(unsigned short)f2bf(p3) << 16);
        uint2 pk; pk.x = u0; pk.y = u1;
        *(uint2*)&Plds[wv*1280 + li*80 + nt*16 + lg*4] = pk;
    }
    csum += __shfl_xor(csum, 16);
    csum += __shfl_xor(csum, 32);

    // ---- PV from LDS V fragments ----
    f32x4 oacc[4] = {};
    #pragma unroll
    for (int kch = 0; kch < 2; ++kch) {
        s16x8 pa = *(const s16x8*)&Plds[wv*1280 + li*80 + kch*32 + lg*8];
        #pragma unroll
        for (int dt = 0; dt < 4; ++dt) {
            s16x8 vb = *(const s16x8*)&Vl[(kch*4 + dt)*512 + l*8];
            oacc[dt] = __builtin_amdgcn_mfma_f32_16x16x32_bf16(pa, vb, oacc[dt], 0, 0, 0);
        }
    }

    // ---- write partials ----
    const size_t SBH = (size_t)B_ * H_ * NSEQ;
    if (lg == 0) {
        mpart[(size_t)sp * SBH + bh * NSEQ + qrow] = cmax;
        lpart[(size_t)sp * SBH + bh * NSEQ + qrow] = csum;
    }
    #pragma unroll
    for (int dt = 0; dt < 4; ++dt)
        #pragma unroll
        for (int r = 0; r < 4; ++r)
            Opart[((size_t)sp * SBH + bh * NSEQ + qt*64 + wv*16 + lg*4 + r) * DKV + dt*16 + li]
                = f2bf(oacc[dt][r]);
}

// ---------------- split combine: merge 16 partials, normalize ----------------
__global__ __launch_bounds__(256, 1) void attn_combine(
    const short* __restrict__ Opart, const float* __restrict__ mpart,
    const float* __restrict__ lpart, short* __restrict__ Ob)
{
    const size_t SBH = (size_t)B_ * H_ * NSEQ;
    const int R = blockIdx.x * 4 + (threadIdx.x >> 6);
    const int d = threadIdx.x & 63;
    const int bh = R >> 10, n = R & (NSEQ - 1);
    const int b = bh >> 4, h = bh & (H_ - 1);

    float ms[NSPLIT], ls[NSPLIT], ov[NSPLIT];
    #pragma unroll
    for (int s = 0; s < NSPLIT; ++s) {
        ms[s] = mpart[(size_t)s * SBH + R];
        ls[s] = lpart[(size_t)s * SBH + R];
        ov[s] = bf2f(Opart[((size_t)s * SBH + R) * DKV + d]);
    }
    float mstar = -1e30f;
    #pragma unroll
    for (int s = 0; s < NSPLIT; ++s) mstar = fmaxf(mstar, ms[s]);
    float lstar = 0.f, acc = 0.f;
    #pragma unroll
    for (int s = 0; s < NSPLIT; ++s) {
        float w = __expf(ms[s] - mstar);
        lstar += w * ls[s];
        acc   += w * ov[s];
    }
    Ob[((size_t)b * NSEQ + n) * DM + h * DKV + d] = f2bf(acc / lstar);
}

// ---------------- residual + LayerNorm ----------------
__global__ __launch_bounds__(256) void ln_kernel(
    const float* __restrict__ Y, const float* __restrict__ gamma,
    const float* __restrict__ beta, float* __restrict__ out)
{
    const int row = blockIdx.x;
    const int t = threadIdx.x;
    const float* y = Y + (size_t)row * DM;
    float4 x = *(const float4*)(y + t*4);
    __shared__ float red[4];
    float s = x.x + x.y + x.z + x.w;
    #pragma unroll
    for (int off = 32; off > 0; off >>= 1) s += __shfl_xor(s, off);
    if ((t & 63) == 0) red[t >> 6] = s;
    __syncthreads();
    float mean = (red[0]+red[1]+red[2]+red[3]) * (1.0f/DM);
    float d0 = x.x-mean, d1 = x.y-mean, d2 = x.z-mean, d3 = x.w-mean;
    float sq = d0*d0 + d1*d1 + d2*d2 + d3*d3;
    __syncthreads();
    #pragma unroll
    for (int off = 32; off > 0; off >>= 1) sq += __shfl_xor(sq, off);
    if ((t & 63) == 0) red[t >> 6] = sq;
    __syncthreads();
    float var = (red[0]+red[1]+red[2]+red[3]) * (1.0f/DM);
    float rstd = rsqrtf(var + LNEPS);
    int c = t * 4;
    float4 g  = *(const float4*)(gamma + c);
    float4 bb = *(const float4*)(beta + c);
    float4 o;
    o.x = d0*rstd*g.x + bb.x;
    o.y = d1*rstd*g.y + bb.y;
    o.z = d2*rstd*g.z + bb.z;
    o.w = d3*rstd*g.w + bb.w;
    *(float4*)(out + (size_t)row*DM + c) = o;
}

extern "C" void kernel_launch(void* const* d_in, const int* in_sizes, int n_in,
                              void* d_out, int out_size, void* d_ws, size_t ws_size,
                              hipStream_t stream)
{
    const float* queries = (const float*)d_in[0];
    const float* keys    = (const float*)d_in[1];
    const float* values  = (const float*)d_in[2];
    const void*  mask    = d_in[3];
    const float* wgt     = (const float*)d_in[4];
    const float* Wq = (const float*)d_in[5];  const float* bq = (const float*)d_in[6];
    const float* Wk = (const float*)d_in[7];  const float* bk = (const float*)d_in[8];
    const float* Wv = (const float*)d_in[9];  const float* bv = (const float*)d_in[10];
    const float* Wo = (const float*)d_in[11]; const float* bo = (const float*)d_in[12];
    const float* gamma = (const float*)d_in[13]; const float* beta = (const float*)d_in[14];
    float* out = (float*)d_out;

    const size_t SZ  = (size_t)B_ * NSEQ * DM;     // 2M elements
    const size_t WSZ = (size_t)DM * DM;            // 1M elements
    const size_t SBH = (size_t)B_ * H_ * NSEQ;     // 32K rows

    char* ws = (char*)d_ws;
    int*   flag = (int*)ws;
    short* Wtq = (short*)(ws + 256);               // Wtq|Wtk|Wtv contiguous = Wcat
    short* Wtk = Wtq + WSZ;
    short* Wtv = Wtk + WSZ;
    short* Wto = Wtv + WSZ;
    short* Qh  = Wto + WSZ;
    short* Kh  = Qh + SZ;
    short* Vth = Kh + SZ;
    short* Opart = Vth + SZ;                       // 16 x 4 MB bf16
    float* mpart = (float*)(Opart + (size_t)NSPLIT * SBH * DKV);
    float* lpart = mpart + NSPLIT * SBH;
    short* Ob  = (short*)(lpart + NSPLIT * SBH);
    float* Yb  = (float*)Opart;                    // alias: Opart dead after combine

    detect_mask<<<1, 1, 0, stream>>>((const unsigned*)mask, flag);
    castT4_bf16<<<dim3(32, 32, 4), 256, 0, stream>>>(Wq, Wk, Wv, Wo, Wtq, Wtk, Wtv, Wto);

    gemm_qkv<<<dim3(48, 32), 256, 0, stream>>>(queries, keys, values, Wtq,
                                               bq, bk, bv, Qh, Kh, Vth);

    attn_one<<<dim3(16 * NSPLIT, H_, B_), 256, 0, stream>>>(
        Qh, Kh, Vth, mask, wgt, flag, Opart, mpart, lpart);
    attn_combine<<<dim3((int)(SBH / 4)), 256, 0, stream>>>(Opart, mpart, lpart, Ob);

    gemm_out<<<dim3(16, 32), 256, 0, stream>>>(Ob, Wto, bo, queries, Yb);
    ln_kernel<<<dim3(B_*NSEQ), 256, 0, stream>>>(Yb, gamma, beta, out);
}

// Round 17
// 161.130 us; speedup vs baseline: 1.3738x; 1.2837x over previous
//
#include <hip/hip_runtime.h>
#include <hip/hip_bf16.h>
#include <math.h>

#define B_   2
#define H_   16
#define NSEQ 1024
#define DM   1024
#define DKV  64
#define NSPLIT 4
#define KPB  (NSEQ / NSPLIT)   // 256 keys per block, 4 chunks of 64
#define LNEPS 1e-5f

typedef __attribute__((ext_vector_type(8))) short s16x8;
typedef __attribute__((ext_vector_type(4))) float f32x4;
typedef __attribute__((ext_vector_type(4))) unsigned u32x4;

__device__ inline short f2bf(float f) {
    __hip_bfloat16 h = __float2bfloat16(f);
    return *reinterpret_cast<short*>(&h);
}
__device__ inline float bf2f(short s) {
    unsigned u = ((unsigned)(unsigned short)s) << 16;
    return __uint_as_float(u);
}

// async global->LDS; LDS dest = wave-uniform base + lane*width; global src per-lane.
__device__ __forceinline__ void gll16(const void* g, void* l) {
    __builtin_amdgcn_global_load_lds(
        (const __attribute__((address_space(1))) unsigned int*)g,
        (__attribute__((address_space(3))) unsigned int*)l, 16, 0, 0);
}

#define SYNC_STAGE do { asm volatile("s_waitcnt vmcnt(0)" ::: "memory"); __syncthreads(); } while (0)

// ---------------- mask dtype detection ----------------
__global__ void detect_mask(const unsigned* __restrict__ mask_words, int* __restrict__ flag) {
    unsigned f = 0;
    for (int i = 0; i < 256; ++i) f |= (mask_words[i] > 1u) ? 1u : 0u;
    *flag = (int)f;   // 1 => packed uint8 bools, 0 => int32 0/1
}

// ---------------- W[K][N] f32 -> Wt[N][K] bf16 (4 weights in one launch) ----------------
__global__ __launch_bounds__(256) void castT4_bf16(
    const float* __restrict__ w0, const float* __restrict__ w1,
    const float* __restrict__ w2, const float* __restrict__ w3,
    short* __restrict__ t0, short* __restrict__ t1,
    short* __restrict__ t2, short* __restrict__ t3) {
    const float* W = blockIdx.z == 0 ? w0 : (blockIdx.z == 1 ? w1 : (blockIdx.z == 2 ? w2 : w3));
    short* Wt      = blockIdx.z == 0 ? t0 : (blockIdx.z == 1 ? t1 : (blockIdx.z == 2 ? t2 : t3));
    __shared__ float tl[32][33];
    const int k0 = blockIdx.y * 32, n0 = blockIdx.x * 32;
    const int r = threadIdx.x >> 3, c4 = (threadIdx.x & 7) * 4;
    *(float4*)&tl[r][c4] = *(const float4*)(W + (size_t)(k0 + r) * DM + n0 + c4);
    __syncthreads();
    unsigned u0 = (unsigned short)f2bf(tl[c4+0][r]) | ((unsigned)(unsigned short)f2bf(tl[c4+1][r]) << 16);
    unsigned u1 = (unsigned short)f2bf(tl[c4+2][r]) | ((unsigned)(unsigned short)f2bf(tl[c4+3][r]) << 16);
    uint2 pk; pk.x = u0; pk.y = u1;
    *(uint2*)(Wt + (size_t)(n0 + r) * DM + k0 + c4) = pk;
}

// ---------------- shared GEMM core pieces ----------------
__device__ inline void loadAf32(const float* p, s16x8& a0, s16x8& a1) {
    f32x4 v0 = *(const f32x4*)p,       v1 = *(const f32x4*)(p + 4);
    f32x4 v2 = *(const f32x4*)(p + 8), v3 = *(const f32x4*)(p + 12);
    a0[0]=f2bf(v0[0]); a0[1]=f2bf(v0[1]); a0[2]=f2bf(v0[2]); a0[3]=f2bf(v0[3]);
    a0[4]=f2bf(v1[0]); a0[5]=f2bf(v1[1]); a0[6]=f2bf(v1[2]); a0[7]=f2bf(v1[3]);
    a1[0]=f2bf(v2[0]); a1[1]=f2bf(v2[1]); a1[2]=f2bf(v2[2]); a1[3]=f2bf(v2[3]);
    a1[4]=f2bf(v3[0]); a1[5]=f2bf(v3[1]); a1[6]=f2bf(v3[2]); a1[7]=f2bf(v3[3]);
}

// ---------------- fused QKV projection: 3 GEMMs in one launch ----------------
__global__ __launch_bounds__(256) void gemm_qkv(
    const float* __restrict__ qin, const float* __restrict__ kin, const float* __restrict__ vin,
    const short* __restrict__ Wcat,     // Wtq|Wtk|Wtv contiguous, each [DM][DM]
    const float* __restrict__ bq, const float* __restrict__ bk, const float* __restrict__ bv,
    short* __restrict__ Qh, short* __restrict__ Kh, short* __restrict__ Vth)
{
    const int t  = threadIdx.x;
    const int wv = t >> 6, l = t & 63, lg = l >> 4, li = l & 15;
    const int wr = wv >> 1, wc = wv & 1;
    const int c0g = blockIdx.x * 64, m0 = blockIdx.y * 64;
    const int sel = c0g >> 10;              // 0=q 1=k 2=v
    const int c0  = c0g & 1023;
    const float* A    = sel == 0 ? qin : (sel == 1 ? kin : vin);
    const short* Wt   = Wcat + (size_t)sel * DM * DM;
    const float* bias = sel == 0 ? bq : (sel == 1 ? bk : bv);
    short* outp       = sel == 0 ? Qh : (sel == 1 ? Kh : Vth);
    const int mode    = sel == 2 ? 2 : 1;

    __shared__ short Asl[64 * 64];
    __shared__ short Bsl[64 * 64];

    f32x4 acc[2][2] = {};
    const int sr = t >> 2, scol = (t & 3) * 16;
    const int sw = (sr & 7) << 3;

    s16x8 a0, a1;
    loadAf32(A + (size_t)(m0 + sr) * DM + scol, a0, a1);
    s16x8 b0 = *(const s16x8*)(Wt + (size_t)(c0 + sr) * DM + scol);
    s16x8 b1 = *(const s16x8*)(Wt + (size_t)(c0 + sr) * DM + scol + 8);

    for (int k0 = 0; k0 < DM; k0 += 64) {
        __syncthreads();
        *(s16x8*)&Asl[sr * 64 + (scol ^ sw)]       = a0;
        *(s16x8*)&Asl[sr * 64 + ((scol + 8) ^ sw)] = a1;
        *(s16x8*)&Bsl[sr * 64 + (scol ^ sw)]       = b0;
        *(s16x8*)&Bsl[sr * 64 + ((scol + 8) ^ sw)] = b1;
        __syncthreads();
        if (k0 + 64 < DM) {
            loadAf32(A + (size_t)(m0 + sr) * DM + k0 + 64 + scol, a0, a1);
            b0 = *(const s16x8*)(Wt + (size_t)(c0 + sr) * DM + k0 + 64 + scol);
            b1 = *(const s16x8*)(Wt + (size_t)(c0 + sr) * DM + k0 + 64 + scol + 8);
        }
        #pragma unroll
        for (int kh = 0; kh < 2; ++kh) {
            s16x8 af[2], bf[2];
            #pragma unroll
            for (int fi = 0; fi < 2; ++fi) {
                const int row = wr * 32 + fi * 16 + li;
                af[fi] = *(const s16x8*)&Asl[row * 64 + ((kh * 32 + lg * 8) ^ ((row & 7) << 3))];
            }
            #pragma unroll
            for (int fj = 0; fj < 2; ++fj) {
                const int row = wc * 32 + fj * 16 + li;
                bf[fj] = *(const s16x8*)&Bsl[row * 64 + ((kh * 32 + lg * 8) ^ ((row & 7) << 3))];
            }
            #pragma unroll
            for (int fi = 0; fi < 2; ++fi)
                #pragma unroll
                for (int fj = 0; fj < 2; ++fj)
                    acc[fi][fj] = __builtin_amdgcn_mfma_f32_16x16x32_bf16(af[fi], bf[fj], acc[fi][fj], 0, 0, 0);
        }
    }

    const int hh = c0 >> 6;
    #pragma unroll
    for (int fi = 0; fi < 2; ++fi) {
        #pragma unroll
        for (int j = 0; j < 4; ++j) {
            const int m = m0 + wr * 32 + fi * 16 + lg * 4 + j;
            const int bb = m >> 10, n = m & (NSEQ - 1);
            #pragma unroll
            for (int fj = 0; fj < 2; ++fj) {
                const int cc = wc * 32 + fj * 16 + li;
                float v = acc[fi][fj][j] + bias[c0 + cc];
                if (mode == 1)
                    outp[(((size_t)(bb * H_ + hh) * NSEQ) + n) * DKV + cc] = f2bf(v);
                else
                    outp[(((size_t)(bb * H_ + hh) * DKV) + cc) * NSEQ + n] = f2bf(v);
            }
        }
    }
}

// ---------------- out-proj GEMM: Yb = Ob @ Wto^T + bo + resid (f32 out) ----------------
__global__ __launch_bounds__(256) void gemm_out(
    const short* __restrict__ A, const short* __restrict__ Wt,
    const float* __restrict__ bias, const float* __restrict__ resid,
    float* __restrict__ outp)
{
    const int t  = threadIdx.x;
    const int wv = t >> 6, l = t & 63, lg = l >> 4, li = l & 15;
    const int wr = wv >> 1, wc = wv & 1;
    const int c0 = blockIdx.x * 64, m0 = blockIdx.y * 64;

    __shared__ short Asl[64 * 64];
    __shared__ short Bsl[64 * 64];

    f32x4 acc[2][2] = {};
    const int sr = t >> 2, scol = (t & 3) * 16;
    const int sw = (sr & 7) << 3;

    s16x8 a0 = *(const s16x8*)(A + (size_t)(m0 + sr) * DM + scol);
    s16x8 a1 = *(const s16x8*)(A + (size_t)(m0 + sr) * DM + scol + 8);
    s16x8 b0 = *(const s16x8*)(Wt + (size_t)(c0 + sr) * DM + scol);
    s16x8 b1 = *(const s16x8*)(Wt + (size_t)(c0 + sr) * DM + scol + 8);

    for (int k0 = 0; k0 < DM; k0 += 64) {
        __syncthreads();
        *(s16x8*)&Asl[sr * 64 + (scol ^ sw)]       = a0;
        *(s16x8*)&Asl[sr * 64 + ((scol + 8) ^ sw)] = a1;
        *(s16x8*)&Bsl[sr * 64 + (scol ^ sw)]       = b0;
        *(s16x8*)&Bsl[sr * 64 + ((scol + 8) ^ sw)] = b1;
        __syncthreads();
        if (k0 + 64 < DM) {
            a0 = *(const s16x8*)(A + (size_t)(m0 + sr) * DM + k0 + 64 + scol);
            a1 = *(const s16x8*)(A + (size_t)(m0 + sr) * DM + k0 + 64 + scol + 8);
            b0 = *(const s16x8*)(Wt + (size_t)(c0 + sr) * DM + k0 + 64 + scol);
            b1 = *(const s16x8*)(Wt + (size_t)(c0 + sr) * DM + k0 + 64 + scol + 8);
        }
        #pragma unroll
        for (int kh = 0; kh < 2; ++kh) {
            s16x8 af[2], bf[2];
            #pragma unroll
            for (int fi = 0; fi < 2; ++fi) {
                const int row = wr * 32 + fi * 16 + li;
                af[fi] = *(const s16x8*)&Asl[row * 64 + ((kh * 32 + lg * 8) ^ ((row & 7) << 3))];
            }
            #pragma unroll
            for (int fj = 0; fj < 2; ++fj) {
                const int row = wc * 32 + fj * 16 + li;
                bf[fj] = *(const s16x8*)&Bsl[row * 64 + ((kh * 32 + lg * 8) ^ ((row & 7) << 3))];
            }
            #pragma unroll
            for (int fi = 0; fi < 2; ++fi)
                #pragma unroll
                for (int fj = 0; fj < 2; ++fj)
                    acc[fi][fj] = __builtin_amdgcn_mfma_f32_16x16x32_bf16(af[fi], bf[fj], acc[fi][fj], 0, 0, 0);
        }
    }

    #pragma unroll
    for (int fi = 0; fi < 2; ++fi) {
        #pragma unroll
        for (int j = 0; j < 4; ++j) {
            const int m = m0 + wr * 32 + fi * 16 + lg * 4 + j;
            #pragma unroll
            for (int fj = 0; fj < 2; ++fj) {
                const int c = c0 + wc * 32 + fj * 16 + li;
                outp[(size_t)m * DM + c] = acc[fi][fj][j] + bias[c] + resid[(size_t)m * DM + c];
            }
        }
    }
}

// ---------------- flash attention: NSPLIT=4, 4-chunk online-softmax loop, full async staging ----
// Round-16 verified staging (K/V frag-linear, wgt row-contiguous+XOR) + round-5 verified
// online softmax. Cuts the Opart tax 4x (64->16 MB write, combine 68->20 MB read).
// Mask staged via 4x gll16 (16 rows x 64B per instr) instead of 16x gll4.
__global__ __launch_bounds__(256) void attn_split(
    const short* __restrict__ Qb, const short* __restrict__ Kb, const short* __restrict__ Vt,
    const void* __restrict__ mask, const float* __restrict__ wgt,
    const int* __restrict__ flagp, short* __restrict__ Opart,
    float* __restrict__ mpart, float* __restrict__ lpart)
{
    const int t  = threadIdx.x;
    const int wv = t >> 6;
    const int l  = t & 63;
    const int lg = l >> 4;
    const int li = l & 15;
    const int qt = blockIdx.x >> 2;          // 0..15
    const int sp = blockIdx.x & (NSPLIT-1);  // 0..3
    const int h  = blockIdx.y, b = blockIdx.z;
    const size_t bh = (size_t)b * H_ + h;
    const int qrow = qt*64 + wv*16 + li;     // softmax-layout row
    const int kbase = sp * KPB;

    __shared__ short Kl[8 * 512];            // 8 KB : frag (dc*4+nt), lane 16B
    __shared__ short Vl[8 * 512];            // 8 KB : frag (kch*4+dt), lane 16B
    __shared__ float Wl[16 * 256];           // 16 KB: instr j = rows 4j..4j+3, XOR-swizzled chunks
    __shared__ unsigned char Ml[4 * 1024];   // 4 KB : instr j = rows 16j..16j+15, 16B chunks
    __shared__ short Plds[4][16][80];        // 10 KB: per-wave P tile

    const short* Qp = Qb + (bh * NSEQ + qt*64 + wv*16) * DKV;
    const short* Kp = Kb + bh * NSEQ * DKV;
    const short* Vp = Vt + bh * DKV * NSEQ;
    const size_t moff = (bh * NSEQ + qrow) * NSEQ;
    const size_t rowT = bh * NSEQ + (size_t)qt * 64;       // tile row base in wgt/mask
    const int mmode = *flagp;
    const unsigned* Mi = (const unsigned*)mask;
    const unsigned char* Mb = (const unsigned char*)mask;

    // staging lane mappings
    const int srow = l >> 4;                  // wgt: sub-row 0..3
    const int schk = (l & 15) ^ srow;         // wgt: swizzled 16B chunk (involution)
    const int mrow = l >> 2;                  // mask: sub-row 0..15
    const int mchk = l & 3;                   // mask: 16B chunk

    // Q fragments (once per block)
    s16x8 qa[2];
    qa[0] = *(const s16x8*)(Qp + (size_t)li * DKV + lg*8);
    qa[1] = *(const s16x8*)(Qp + (size_t)li * DKV + 32 + lg*8);

    float m_run = -1e30f, l_run = 0.f;
    f32x4 oacc[4] = {};
    const int rq = li >> 2, rs = li & 3;

    for (int c = 0; c < NSPLIT; ++c) {
        const int kc = kbase + c * 64;

        __syncthreads();   // all waves done reading previous chunk's LDS
        if (wv == 0) {
            #pragma unroll
            for (int i = 0; i < 8; ++i) {    // K frag i = dc*4+nt
                const int nt = i & 3, dc = i >> 2;
                gll16(Kp + (size_t)(kc + nt*16 + li) * DKV + dc*32 + lg*8, Kl + i*512);
            }
        } else if (wv == 1) {
            #pragma unroll
            for (int i = 0; i < 8; ++i) {    // V frag i = kch*4+dt
                const int dt = i & 3, kch = i >> 2;
                gll16(Vp + (size_t)(dt*16 + li) * NSEQ + kc + kch*32 + lg*8, Vl + i*512);
            }
        } else if (wv == 2) {
            #pragma unroll
            for (int j = 0; j < 8; ++j)
                gll16(wgt + (rowT + j*4 + srow) * NSEQ + kc + schk*4, Wl + j*256);
            #pragma unroll
            for (int j = 0; j < 2; ++j)
                gll16(Mb + (rowT + j*16 + mrow) * NSEQ + kc + mchk*16, Ml + j*1024);
        } else {
            #pragma unroll
            for (int j = 8; j < 16; ++j)
                gll16(wgt + (rowT + j*4 + srow) * NSEQ + kc + schk*4, Wl + j*256);
            #pragma unroll
            for (int j = 2; j < 4; ++j)
                gll16(Mb + (rowT + j*16 + mrow) * NSEQ + kc + mchk*16, Ml + j*1024);
        }
        SYNC_STAGE;

        // ---- S^T = K * Q^T : sc[nt][r] = S[q=li][key = kc + nt*16 + lg*4 + r] ----
        f32x4 sc[4] = {};
        #pragma unroll
        for (int dc = 0; dc < 2; ++dc)
            #pragma unroll
            for (int nt = 0; nt < 4; ++nt) {
                s16x8 kb = *(const s16x8*)&Kl[(dc*4 + nt)*512 + l*8];
                sc[nt] = __builtin_amdgcn_mfma_f32_16x16x32_bf16(kb, qa[dc], sc[nt], 0, 0, 0);
            }

        // ---- chunk softmax inputs from LDS ----
        float sv[16];
        float cmax = -1e30f;
        #pragma unroll
        for (int nt = 0; nt < 4; ++nt) {
            const int pos = ((nt*4 + lg) ^ rs) * 4;
            f32x4 w4 = *(const f32x4*)&Wl[(wv*4 + rq)*256 + rs*64 + pos];
            unsigned mm[4];
            if (mmode) {
                unsigned u = *(const unsigned*)&Ml[wv*1024 + (li*4 + nt)*16 + lg*4];
                mm[0] = u & 0xffu; mm[1] = (u >> 8) & 0xffu;
                mm[2] = (u >> 16) & 0xffu; mm[3] = u >> 24;
            } else {
                u32x4 mi = *(const u32x4*)(Mi + moff + kc + nt*16 + lg*4);
                mm[0] = mi[0]; mm[1] = mi[1]; mm[2] = mi[2]; mm[3] = mi[3];
            }
            #pragma unroll
            for (int r = 0; r < 4; ++r) {
                float s = sc[nt][r] * 0.125f * w4[r];
                s = mm[r] ? -1e30f : s;
                sv[nt*4 + r] = s;
                cmax = fmaxf(cmax, s);
            }
        }
        cmax = fmaxf(cmax, __shfl_xor(cmax, 16));
        cmax = fmaxf(cmax, __shfl_xor(cmax, 32));
        const float mnew = fmaxf(m_run, cmax);
        const float factor = __expf(m_run - mnew);
        m_run = mnew;

        float csum = 0.f;
        #pragma unroll
        for (int nt = 0; nt < 4; ++nt) {
            float p0 = __expf(sv[nt*4+0] - mnew), p1 = __expf(sv[nt*4+1] - mnew);
            float p2 = __expf(sv[nt*4+2] - mnew), p3 = __expf(sv[nt*4+3] - mnew);
            csum += p0 + p1 + p2 + p3;
            unsigned u0 = (unsigned short)f2bf(p0) | ((unsigned)(unsigned short)f2bf(p1) << 16);
            unsigned u1 = (unsigned short)f2bf(p2) | ((unsigned)(unsigned short)f2bf(p3) << 16);
            uint2 pk; pk.x = u0; pk.y = u1;
            *(uint2*)&Plds[wv][li][nt*16 + lg*4] = pk;
        }
        csum += __shfl_xor(csum, 16);
        csum += __shfl_xor(csum, 32);
        l_run = l_run * factor + csum;

        // rescale O in C layout (factor from lane lg*4+r)
        float ffac[4];
        #pragma unroll
        for (int r = 0; r < 4; ++r) ffac[r] = __shfl(factor, lg*4 + r);
        #pragma unroll
        for (int dt = 0; dt < 4; ++dt)
            #pragma unroll
            for (int r = 0; r < 4; ++r)
                oacc[dt][r] *= ffac[r];

        // ---- PV from LDS V fragments ----
        #pragma unroll
        for (int kch = 0; kch < 2; ++kch) {
            s16x8 pa = *(const s16x8*)&Plds[wv][li][kch*32 + lg*8];
            #pragma unroll
            for (int dt = 0; dt < 4; ++dt) {
                s16x8 vb = *(const s16x8*)&Vl[(kch*4 + dt)*512 + l*8];
                oacc[dt] = __builtin_amdgcn_mfma_f32_16x16x32_bf16(pa, vb, oacc[dt], 0, 0, 0);
            }
        }
    }

    // ---- write partials ----
    const size_t SBH = (size_t)B_ * H_ * NSEQ;
    if (lg == 0) {
        mpart[(size_t)sp * SBH + bh * NSEQ + qrow] = m_run;
        lpart[(size_t)sp * SBH + bh * NSEQ + qrow] = l_run;
    }
    #pragma unroll
    for (int dt = 0; dt < 4; ++dt)
        #pragma unroll
        for (int r = 0; r < 4; ++r)
            Opart[((size_t)sp * SBH + bh * NSEQ + qt*64 + wv*16 + lg*4 + r) * DKV + dt*16 + li]
                = f2bf(oacc[dt][r]);
}

// ---------------- split combine: merge 4 partials, normalize ----------------
__global__ __launch_bounds__(256, 1) void attn_combine(
    const short* __restrict__ Opart, const float* __restrict__ mpart,
    const float* __restrict__ lpart, short* __restrict__ Ob)
{
    const size_t SBH = (size_t)B_ * H_ * NSEQ;
    const int R = blockIdx.x * 4 + (threadIdx.x >> 6);
    const int d = threadIdx.x & 63;
    const int bh = R >> 10, n = R & (NSEQ - 1);
    const int b = bh >> 4, h = bh & (H_ - 1);

    float ms[NSPLIT], ls[NSPLIT], ov[NSPLIT];
    #pragma unroll
    for (int s = 0; s < NSPLIT; ++s) {
        ms[s] = mpart[(size_t)s * SBH + R];
        ls[s] = lpart[(size_t)s * SBH + R];
        ov[s] = bf2f(Opart[((size_t)s * SBH + R) * DKV + d]);
    }
    float mstar = -1e30f;
    #pragma unroll
    for (int s = 0; s < NSPLIT; ++s) mstar = fmaxf(mstar, ms[s]);
    float lstar = 0.f, acc = 0.f;
    #pragma unroll
    for (int s = 0; s < NSPLIT; ++s) {
        float w = __expf(ms[s] - mstar);
        lstar += w * ls[s];
        acc   += w * ov[s];
    }
    Ob[((size_t)b * NSEQ + n) * DM + h * DKV + d] = f2bf(acc / lstar);
}

// ---------------- residual + LayerNorm ----------------
__global__ __launch_bounds__(256) void ln_kernel(
    const float* __restrict__ Y, const float* __restrict__ gamma,
    const float* __restrict__ beta, float* __restrict__ out)
{
    const int row = blockIdx.x;
    const int t = threadIdx.x;
    const float* y = Y + (size_t)row * DM;
    float4 x = *(const float4*)(y + t*4);
    __shared__ float red[4];
    float s = x.x + x.y + x.z + x.w;
    #pragma unroll
    for (int off = 32; off > 0; off >>= 1) s += __shfl_xor(s, off);
    if ((t & 63) == 0) red[t >> 6] = s;
    __syncthreads();
    float mean = (red[0]+red[1]+red[2]+red[3]) * (1.0f/DM);
    float d0 = x.x-mean, d1 = x.y-mean, d2 = x.z-mean, d3 = x.w-mean;
    float sq = d0*d0 + d1*d1 + d2*d2 + d3*d3;
    __syncthreads();
    #pragma unroll
    for (int off = 32; off > 0; off >>= 1) sq += __shfl_xor(sq, off);
    if ((t & 63) == 0) red[t >> 6] = sq;
    __syncthreads();
    float var = (red[0]+red[1]+red[2]+red[3]) * (1.0f/DM);
    float rstd = rsqrtf(var + LNEPS);
    int c = t * 4;
    float4 g  = *(const float4*)(gamma + c);
    float4 bb = *(const float4*)(beta + c);
    float4 o;
    o.x = d0*rstd*g.x + bb.x;
    o.y = d1*rstd*g.y + bb.y;
    o.z = d2*rstd*g.z + bb.z;
    o.w = d3*rstd*g.w + bb.w;
    *(float4*)(out + (size_t)row*DM + c) = o;
}

extern "C" void kernel_launch(void* const* d_in, const int* in_sizes, int n_in,
                              void* d_out, int out_size, void* d_ws, size_t ws_size,
                              hipStream_t stream)
{
    const float* queries = (const float*)d_in[0];
    const float* keys    = (const float*)d_in[1];
    const float* values  = (const float*)d_in[2];
    const void*  mask    = d_in[3];
    const float* wgt     = (const float*)d_in[4];
    const float* Wq = (const float*)d_in[5];  const float* bq = (const float*)d_in[6];
    const float* Wk = (const float*)d_in[7];  const float* bk = (const float*)d_in[8];
    const float* Wv = (const float*)d_in[9];  const float* bv = (const float*)d_in[10];
    const float* Wo = (const float*)d_in[11]; const float* bo = (const float*)d_in[12];
    const float* gamma = (const float*)d_in[13]; const float* beta = (const float*)d_in[14];
    float* out = (float*)d_out;

    const size_t SZ  = (size_t)B_ * NSEQ * DM;     // 2M elements
    const size_t WSZ = (size_t)DM * DM;            // 1M elements
    const size_t SBH = (size_t)B_ * H_ * NSEQ;     // 32K rows

    char* ws = (char*)d_ws;
    int*   flag = (int*)ws;
    short* Wtq = (short*)(ws + 256);               // Wtq|Wtk|Wtv contiguous = Wcat
    short* Wtk = Wtq + WSZ;
    short* Wtv = Wtk + WSZ;
    short* Wto = Wtv + WSZ;
    short* Qh  = Wto + WSZ;
    short* Kh  = Qh + SZ;
    short* Vth = Kh + SZ;
    short* Opart = Vth + SZ;                       // 4 x 4 MB bf16
    float* mpart = (float*)(Opart + (size_t)NSPLIT * SBH * DKV);
    float* lpart = mpart + NSPLIT * SBH;
    short* Ob  = (short*)(lpart + NSPLIT * SBH);
    float* Yb  = (float*)Opart;                    // alias: Opart dead after combine

    detect_mask<<<1, 1, 0, stream>>>((const unsigned*)mask, flag);
    castT4_bf16<<<dim3(32, 32, 4), 256, 0, stream>>>(Wq, Wk, Wv, Wo, Wtq, Wtk, Wtv, Wto);

    gemm_qkv<<<dim3(48, 32), 256, 0, stream>>>(queries, keys, values, Wtq,
                                               bq, bk, bv, Qh, Kh, Vth);

    attn_split<<<dim3(16 * NSPLIT, H_, B_), 256, 0, stream>>>(
        Qh, Kh, Vth, mask, wgt, flag, Opart, mpart, lpart);
    attn_combine<<<dim3((int)(SBH / 4)), 256, 0, stream>>>(Opart, mpart, lpart, Ob);

    gemm_out<<<dim3(16, 32), 256, 0, stream>>>(Ob, Wto, bo, queries, Yb);
    ln_kernel<<<dim3(B_*NSEQ), 256, 0, stream>>>(Yb, gamma, beta, out);
}